// Round 1
// baseline (125.598 us; speedup 1.0000x reference)
//
#include <hip/hip_runtime.h>

// SO3SelfInteraction: y[a,k,f] = sum_e Wcg[e] * x[a,i1[e],f] * x[a,i2[e],f]
// with entries scattered over idx_out. LMAX=2 -> S=9, N_ATOMS=32000, N_FEAT=128.
//
// Strategy:
//  - prep kernel (1 thread): counting-sort the ~O(100) sparse CG entries by
//    idx_out into d_ws, folding weight[widx1,widx2]*cg_vals into one coeff.
//    Deterministic every call (harness may replay).
//  - main kernel: block = 256 threads = 8 atoms x 32 float4-columns.
//    Stage x[atom, 0..8, f4] into LDS via global_load_lds (runtime-indexable).
//    For k = 0..8 (compile-time): register float4 accumulator over the k's
//    entry segment (runtime bounds, wave-uniform), direct coalesced store.
//    No scatter, no atomics, no LDS accumulator.

#define S9 9
#define NFEAT 128
#define ATOMS_PER_BLOCK 8
#define THREADS 256

// d_ws layout in 32-bit words:
//   [0 .. 15]      : seg[10] (segment starts per output index k, seg[9]=nnz)
//   [1024 .. ]     : sorted idx_1
//   [2048 .. ]     : sorted idx_2
//   [3072 .. ]     : sorted Wcg (float)
// max nnz is 729 (9^3), so regions never overlap.

__global__ void so3_prep_kernel(const float* __restrict__ weight,
                                const float* __restrict__ cg_vals,
                                const int* __restrict__ idx_1,
                                const int* __restrict__ idx_2,
                                const int* __restrict__ idx_out,
                                const int* __restrict__ widx_1,
                                const int* __restrict__ widx_2,
                                int nnz, int* __restrict__ ws) {
    if (threadIdx.x != 0 || blockIdx.x != 0) return;
    int* seg   = ws;
    int* o_i1  = ws + 1024;
    int* o_i2  = ws + 2048;
    float* o_w = (float*)(ws + 3072);
    int pos = 0;
    for (int k = 0; k < S9; ++k) {
        seg[k] = pos;
        for (int e = 0; e < nnz; ++e) {
            if (idx_out[e] == k) {
                o_i1[pos] = idx_1[e];
                o_i2[pos] = idx_2[e];
                o_w[pos]  = weight[widx_1[e] * 3 + widx_2[e]] * cg_vals[e];
                ++pos;
            }
        }
    }
    seg[S9] = pos;
}

__global__ __launch_bounds__(THREADS) void so3_main_kernel(
        const float* __restrict__ x,
        const int* __restrict__ ws,
        float* __restrict__ y) {
    __shared__ __align__(16) float xs[S9 * THREADS * 4];

    const int tid  = threadIdx.x;
    const int atom = blockIdx.x * ATOMS_PER_BLOCK + (tid >> 5);
    const int c4   = tid & 31;                       // float4 column within row
    const size_t rowBase = (size_t)atom * S9 * NFEAT + (size_t)c4 * 4;

    // Stage this block's 8 atoms x 9 s-rows into LDS.
    // LDS dest = s*4096B-block + tid*16 : wave-uniform base + lane*16 (required
    // by global_load_lds); global src is the matching per-lane address.
    #pragma unroll
    for (int s = 0; s < S9; ++s) {
        const float* src = x + rowBase + (size_t)s * NFEAT;
        float* dst = &xs[s * (THREADS * 4) + tid * 4];
        __builtin_amdgcn_global_load_lds(
            (const __attribute__((address_space(1))) unsigned int*)src,
            (__attribute__((address_space(3))) unsigned int*)dst,
            16, 0, 0);
    }
    __syncthreads();   // compiler drains vmcnt before s_barrier

    const int* seg   = ws;
    const int* e_i1  = ws + 1024;
    const int* e_i2  = ws + 2048;
    const float* e_w = (const float*)(ws + 3072);

    #pragma unroll
    for (int k = 0; k < S9; ++k) {
        float4 acc = make_float4(0.f, 0.f, 0.f, 0.f);
        const int eBeg = __builtin_amdgcn_readfirstlane(seg[k]);
        const int eEnd = __builtin_amdgcn_readfirstlane(seg[k + 1]);
        for (int e = eBeg; e < eEnd; ++e) {
            const float w = e_w[e];
            const int i1 = e_i1[e];
            const int i2 = e_i2[e];
            const float4 a4 = *reinterpret_cast<const float4*>(
                &xs[i1 * (THREADS * 4) + tid * 4]);
            const float4 b4 = *reinterpret_cast<const float4*>(
                &xs[i2 * (THREADS * 4) + tid * 4]);
            acc.x = fmaf(w, a4.x * b4.x, acc.x);
            acc.y = fmaf(w, a4.y * b4.y, acc.y);
            acc.z = fmaf(w, a4.z * b4.z, acc.z);
            acc.w = fmaf(w, a4.w * b4.w, acc.w);
        }
        *reinterpret_cast<float4*>(y + rowBase + (size_t)k * NFEAT) = acc;
    }
}

extern "C" void kernel_launch(void* const* d_in, const int* in_sizes, int n_in,
                              void* d_out, int out_size, void* d_ws, size_t ws_size,
                              hipStream_t stream) {
    const float* x       = (const float*)d_in[0];
    const float* weight  = (const float*)d_in[1];
    const float* cg_vals = (const float*)d_in[2];
    const int* idx_1     = (const int*)d_in[3];
    const int* idx_2     = (const int*)d_in[4];
    const int* idx_out   = (const int*)d_in[5];
    const int* widx_1    = (const int*)d_in[6];
    const int* widx_2    = (const int*)d_in[7];
    float* y             = (float*)d_out;
    int* ws              = (int*)d_ws;

    const int nnz     = in_sizes[2];
    const int n_atoms = in_sizes[0] / (S9 * NFEAT);   // 32000

    so3_prep_kernel<<<1, 64, 0, stream>>>(weight, cg_vals, idx_1, idx_2,
                                          idx_out, widx_1, widx_2, nnz, ws);

    const int grid = n_atoms / ATOMS_PER_BLOCK;       // 4000
    so3_main_kernel<<<grid, THREADS, 0, stream>>>(x, ws, y);
}

// Round 2
// 64.192 us; speedup vs baseline: 1.9566x; 1.9566x over previous
//
#include <hip/hip_runtime.h>

// SO3SelfInteraction: y[a,k,f] = sum_e Wcg[e] * x[a,i1[e],f] * x[a,i2[e],f]
// LMAX=2 -> S=9, N_ATOMS=32000, N_FEAT=128.
//
// R1 changes vs R0:
//  - prep is parallel (1 block, LDS atomics; <=2 float adds per cell so
//    bitwise deterministic) instead of 1-thread O(9*nnz) serial scan (~30us).
//  - symmetric (i,j)/(j,i) entries merged via commutativity of x_i*x_j into
//    upper-triangle entries with summed weight -> halves LDS reads + FMAs.
//  - entries packed as uint2 {byte_off_i | byte_off_j<<16, w_bits}; segments
//    padded to multiples of 4 -> inner loop unrolls by 4 (ILP, no tail).

#define S9 9
#define NFEAT 128
#define ATOMS_PER_BLOCK 8
#define THREADS 256
#define ROW_BYTES (THREADS * 16)   // 4096 B per s-row in LDS

// d_ws layout (32-bit words):
//   [0..15]  : seg[10] (entry start per output k, multiples of 4; seg[9]=end)
//   [32.. ]  : packed entries, uint2 each (cap: 9*48 = 432 entries, 3456 B)

__global__ void so3_prep_kernel(const float* __restrict__ weight,
                                const float* __restrict__ cg_vals,
                                const int* __restrict__ idx_1,
                                const int* __restrict__ idx_2,
                                const int* __restrict__ idx_out,
                                const int* __restrict__ widx_1,
                                const int* __restrict__ widx_2,
                                int nnz, int* __restrict__ ws) {
    __shared__ float d[S9 * 81];          // [k][a][b] merged coefficients
    __shared__ int   segs[S9 + 1];
    const int tid = threadIdx.x;

    for (int i = tid; i < S9 * 81; i += THREADS) d[i] = 0.f;
    __syncthreads();

    for (int e = tid; e < nnz; e += THREADS) {
        const int i = idx_1[e];
        const int j = idx_2[e];
        const int k = idx_out[e];
        const float w = weight[widx_1[e] * 3 + widx_2[e]] * cg_vals[e];
        const int a = min(i, j);
        const int b = max(i, j);
        atomicAdd(&d[k * 81 + a * 9 + b], w);   // <=2 adds/cell -> deterministic
    }
    __syncthreads();

    // per-k padded counts -> segment starts (thread 0, trivial)
    if (tid == 0) {
        int pos = 0;
        for (int k = 0; k < S9; ++k) {
            segs[k] = pos;
            int c = 0;
            for (int a = 0; a < S9; ++a)
                for (int b = a; b < S9; ++b)
                    if (d[k * 81 + a * 9 + b] != 0.f) ++c;
            pos += (c + 3) & ~3;                 // pad to multiple of 4
        }
        segs[S9] = pos;
        for (int k = 0; k <= S9; ++k) ws[k] = segs[k];
    }
    __syncthreads();

    // emit entries (9 threads, one k each)
    if (tid < S9) {
        const int k = tid;
        uint2* tab = (uint2*)(ws + 32);
        int pos = segs[k];
        for (int a = 0; a < S9; ++a)
            for (int b = a; b < S9; ++b) {
                const float v = d[k * 81 + a * 9 + b];
                if (v != 0.f) {
                    uint2 t;
                    t.x = (unsigned)(a * ROW_BYTES) | ((unsigned)(b * ROW_BYTES) << 16);
                    t.y = __float_as_uint(v);
                    tab[pos++] = t;
                }
            }
        for (; pos < segs[k + 1]; ++pos) tab[pos] = make_uint2(0u, 0u);  // zero pad
    }
}

__global__ __launch_bounds__(THREADS) void so3_main_kernel(
        const float* __restrict__ x,
        const int* __restrict__ ws,
        float* __restrict__ y) {
    __shared__ __align__(16) float xs[S9 * THREADS * 4];

    const int tid  = threadIdx.x;
    const int atom = blockIdx.x * ATOMS_PER_BLOCK + (tid >> 5);
    const int c4   = tid & 31;
    const size_t rowBase = (size_t)atom * S9 * NFEAT + (size_t)c4 * 4;

    // Stage 8 atoms x 9 s-rows; LDS dest is wave-uniform base + lane*16.
    #pragma unroll
    for (int s = 0; s < S9; ++s) {
        const float* src = x + rowBase + (size_t)s * NFEAT;
        float* dst = &xs[s * (THREADS * 4) + tid * 4];
        __builtin_amdgcn_global_load_lds(
            (const __attribute__((address_space(1))) unsigned int*)src,
            (__attribute__((address_space(3))) unsigned int*)dst,
            16, 0, 0);
    }
    __syncthreads();

    const char* base = (const char*)xs + tid * 16;
    const uint2* __restrict__ tab = (const uint2*)(ws + 32);

    #pragma unroll
    for (int k = 0; k < S9; ++k) {
        float4 acc = make_float4(0.f, 0.f, 0.f, 0.f);
        const int eBeg = __builtin_amdgcn_readfirstlane(ws[k]);
        const int eEnd = __builtin_amdgcn_readfirstlane(ws[k + 1]);
        for (int e = eBeg; e < eEnd; e += 4) {
            #pragma unroll
            for (int u = 0; u < 4; ++u) {
                const uint2 t = tab[e + u];
                const float4 a4 = *reinterpret_cast<const float4*>(base + (t.x & 0xFFFFu));
                const float4 b4 = *reinterpret_cast<const float4*>(base + (t.x >> 16));
                const float w = __uint_as_float(t.y);
                acc.x = fmaf(w * a4.x, b4.x, acc.x);
                acc.y = fmaf(w * a4.y, b4.y, acc.y);
                acc.z = fmaf(w * a4.z, b4.z, acc.z);
                acc.w = fmaf(w * a4.w, b4.w, acc.w);
            }
        }
        *reinterpret_cast<float4*>(y + rowBase + (size_t)k * NFEAT) = acc;
    }
}

extern "C" void kernel_launch(void* const* d_in, const int* in_sizes, int n_in,
                              void* d_out, int out_size, void* d_ws, size_t ws_size,
                              hipStream_t stream) {
    const float* x       = (const float*)d_in[0];
    const float* weight  = (const float*)d_in[1];
    const float* cg_vals = (const float*)d_in[2];
    const int* idx_1     = (const int*)d_in[3];
    const int* idx_2     = (const int*)d_in[4];
    const int* idx_out   = (const int*)d_in[5];
    const int* widx_1    = (const int*)d_in[6];
    const int* widx_2    = (const int*)d_in[7];
    float* y             = (float*)d_out;
    int* ws              = (int*)d_ws;

    const int nnz     = in_sizes[2];
    const int n_atoms = in_sizes[0] / (S9 * NFEAT);   // 32000

    so3_prep_kernel<<<1, THREADS, 0, stream>>>(weight, cg_vals, idx_1, idx_2,
                                               idx_out, widx_1, widx_2, nnz, ws);

    const int grid = n_atoms / ATOMS_PER_BLOCK;       // 4000
    so3_main_kernel<<<grid, THREADS, 0, stream>>>(x, ws, y);
}